// Round 6
// baseline (358.590 us; speedup 1.0000x reference)
//
#include <hip/hip_runtime.h>
#include <stdint.h>

#define NN 50000
#define NE 800000
#define DD 128
#define BN_EPS 1e-5f

typedef __attribute__((ext_vector_type(8))) short bf16x8;
typedef __attribute__((ext_vector_type(4))) float f32x4;

static __device__ __forceinline__ unsigned short f2bf(float f) {
  unsigned u = __float_as_uint(f);
  u += 0x7fffu + ((u >> 16) & 1u);
  return (unsigned short)(u >> 16);
}
static __device__ __forceinline__ float bf2f(unsigned short s) {
  return __uint_as_float(((unsigned)s) << 16);
}

// ---- phase 1: degree count (in-degree, self-loop added later as +1) ----
__global__ __launch_bounds__(256) void k_deg(const int* __restrict__ dst, int* __restrict__ deg) {
  int e = blockIdx.x * 256 + threadIdx.x;
  if (e < NE) atomicAdd(&deg[dst[e]], 1);
}

__global__ __launch_bounds__(256) void k_dinv(const int* __restrict__ deg, float* __restrict__ dinv) {
  int i = blockIdx.x * 256 + threadIdx.x;
  if (i < NN) dinv[i] = rsqrtf((float)(deg[i] + 1));  // +1 self-loop; always >0
}

// ---- phase 2: exclusive scan of degrees -> CSR row offsets (single block) ----
__global__ __launch_bounds__(1024) void k_scan(const int* __restrict__ deg, int* __restrict__ offs) {
  __shared__ int sums[1024];
  const int CH = (NN + 1023) / 1024;  // 49
  int t = threadIdx.x;
  int beg = t * CH;
  int end = min(beg + CH, NN);
  int s = 0;
  for (int i = beg; i < end; ++i) s += deg[i];
  sums[t] = s;
  __syncthreads();
  for (int off = 1; off < 1024; off <<= 1) {  // Hillis-Steele inclusive scan
    int v = (t >= off) ? sums[t - off] : 0;
    __syncthreads();
    sums[t] += v;
    __syncthreads();
  }
  int run = (t == 0) ? 0 : sums[t - 1];
  for (int i = beg; i < end; ++i) { offs[i] = run; run += deg[i]; }
  if (t == 1023) offs[NN] = run;  // == NE (tail chunks are empty)
}

// ---- phase 3: bucket-scatter edges into CSR by dst ----
__global__ __launch_bounds__(256) void k_scatter(const int* __restrict__ src, const int* __restrict__ dst,
                                                 const int* __restrict__ offs, int* __restrict__ cur,
                                                 int* __restrict__ csr) {
  int e = blockIdx.x * 256 + threadIdx.x;
  if (e < NE) {
    int d = dst[e];
    int slot = atomicAdd(&cur[d], 1);
    csr[offs[d] + slot] = src[e];
  }
}

// ---- phase 4: fused dual GEMM  h = x@W.T (bf16 out, ws)  and  res = x@res_W.T (f32, d_out) ----
// mfma_f32_16x16x32_bf16. A: row=lane&15, k=(lane>>4)*8+i. B: col=lane&15, k=(lane>>4)*8+i.
// C/D: col=lane&15, row=(lane>>4)*4+reg  [measured: learn_hip m89].
__global__ __launch_bounds__(256) void k_gemm(const float* __restrict__ x,
                                              const float* __restrict__ W,
                                              const float* __restrict__ resW,
                                              unsigned short* __restrict__ hbf,
                                              float* __restrict__ resout) {
  __shared__ unsigned short Bl[128][136];  // +8 bf16 pad: row stride 272B = 16B-aligned, ~2-way banks (free)
  const int tid = threadIdx.x;
  const int wave = tid >> 6, lane = tid & 63;
  const int rt = blockIdx.x * 4 + wave;    // 16-row tile per wave
  const int rl = lane & 15, kg = lane >> 4;
  const bool valid = rt < (NN / 16);       // NN divisible by 16
  bf16x8 a[4];
  if (valid) {
    const int grow = rt * 16 + rl;
    for (int ks = 0; ks < 4; ++ks) {
      const float* xp = x + (size_t)grow * DD + ks * 32 + kg * 8;
      float4 v0 = *(const float4*)xp;
      float4 v1 = *(const float4*)(xp + 4);
      bf16x8 af;
      af[0] = (short)f2bf(v0.x); af[1] = (short)f2bf(v0.y);
      af[2] = (short)f2bf(v0.z); af[3] = (short)f2bf(v0.w);
      af[4] = (short)f2bf(v1.x); af[5] = (short)f2bf(v1.y);
      af[6] = (short)f2bf(v1.z); af[7] = (short)f2bf(v1.w);
      a[ks] = af;
    }
  }
  for (int pass = 0; pass < 2; ++pass) {   // pass0: W -> h(bf16); pass1: res_W -> d_out(f32)
    const float* Wp = pass ? resW : W;
    __syncthreads();
    for (int idx = tid; idx < DD * DD; idx += 256) {
      Bl[idx >> 7][idx & 127] = f2bf(Wp[idx]);  // B[k][col] = W[col][k] => rows of W as-is
    }
    __syncthreads();
    if (!valid) continue;
    for (int ct = 0; ct < 8; ++ct) {
      f32x4 acc = {0.f, 0.f, 0.f, 0.f};
      for (int ks = 0; ks < 4; ++ks) {
        bf16x8 b = *(const bf16x8*)&Bl[ct * 16 + rl][ks * 32 + kg * 8];
        acc = __builtin_amdgcn_mfma_f32_16x16x32_bf16(a[ks], b, acc, 0, 0, 0);
      }
      const int col = ct * 16 + rl;
      for (int r = 0; r < 4; ++r) {
        const int row = rt * 16 + kg * 4 + r;
        if (pass == 0) hbf[(size_t)row * DD + col] = f2bf(acc[r]);
        else           resout[(size_t)row * DD + col] = acc[r];
      }
    }
  }
}

// ---- phase 5: per-node aggregation. One wave owns one dst node; lane covers 2 cols. ----
__global__ __launch_bounds__(256) void k_agg(const unsigned short* __restrict__ hbf,
                                             const float* __restrict__ dinv,
                                             const int* __restrict__ offs,
                                             const int* __restrict__ csr,
                                             const float* __restrict__ bias,
                                             float* __restrict__ out) {
  const int wave = threadIdx.x >> 6, lane = threadIdx.x & 63;
  const int i = blockIdx.x * 4 + wave;
  if (i >= NN) return;
  const float di = dinv[i];
  const int c0 = lane * 2;
  const unsigned hv = *(const unsigned*)&hbf[(size_t)i * DD + c0];  // self-loop term
  const float w = di * di;
  float ax = bf2f((unsigned short)(hv & 0xffffu)) * w;
  float ay = bf2f((unsigned short)(hv >> 16)) * w;
  const int beg = offs[i], end = offs[i + 1];
  for (int base = beg; base < end; base += 64) {
    const int e = base + lane;
    int s = 0; float nrm = 0.f;
    if (e < end) { s = csr[e]; nrm = dinv[s] * di; }  // batch 64 edge headers per wave
    const int cnt = min(64, end - base);
    for (int d = 0; d < cnt; ++d) {
      const int ss = __shfl(s, d);
      const float nn = __shfl(nrm, d);
      const unsigned hh = *(const unsigned*)&hbf[(size_t)ss * DD + c0];  // coalesced 256B/row
      ax += bf2f((unsigned short)(hh & 0xffffu)) * nn;
      ay += bf2f((unsigned short)(hh >> 16)) * nn;
    }
  }
  float2 r = *(const float2*)&out[(size_t)i * DD + c0];  // res projection from GEMM pass1
  r.x += ax + bias[c0];
  r.y += ay + bias[c0 + 1];
  *(float2*)&out[(size_t)i * DD + c0] = r;
}

// ---- phase 6: BN column stats, two-stage (block partials -> tiny reduce) ----
__global__ __launch_bounds__(256) void k_stats(const float* __restrict__ out, float2* __restrict__ part) {
  const int t = threadIdx.x;
  const int g = blockIdx.x * 256 + t;  // 512 blocks => 1024 threads per column
  const int c = g & 127;
  float s = 0.f, q = 0.f;
  for (int r = g >> 7; r < NN; r += 1024) {
    const float v = out[(size_t)r * DD + c];
    s += v; q += v * v;
  }
  __shared__ float2 red[256];
  red[t] = make_float2(s, q);
  __syncthreads();
  if (t < 128) {
    float2 a = red[t], b = red[t + 128];
    part[blockIdx.x * 128 + t] = make_float2(a.x + b.x, a.y + b.y);
  }
}

__global__ __launch_bounds__(128) void k_statfin(const float2* __restrict__ part,
                                                 const float* __restrict__ gamma,
                                                 const float* __restrict__ beta,
                                                 float* __restrict__ scale,
                                                 float* __restrict__ shift) {
  const int c = threadIdx.x;
  float s = 0.f, q = 0.f;
  for (int b = 0; b < 512; ++b) { float2 p = part[b * 128 + c]; s += p.x; q += p.y; }
  const float mean = s * (1.0f / NN);
  const float var = q * (1.0f / NN) - mean * mean;  // jnp.var is biased (divide by N)
  const float inv = rsqrtf(var + BN_EPS);
  const float sc = gamma[c] * inv;
  scale[c] = sc;
  shift[c] = beta[c] - mean * sc;
}

// ---- phase 7: BN apply + ReLU, in place on d_out ----
__global__ __launch_bounds__(256) void k_bnrelu(float* __restrict__ out,
                                                const float* __restrict__ scale,
                                                const float* __restrict__ shift) {
  const int g = blockIdx.x * 256 + threadIdx.x;  // exactly NN*DD/4 threads
  const int c0 = (g & 31) * 4;
  float4 v = *(float4*)&out[(size_t)g * 4];
  const float4 sc = *(const float4*)&scale[c0];
  const float4 sh = *(const float4*)&shift[c0];
  v.x = fmaxf(v.x * sc.x + sh.x, 0.f);
  v.y = fmaxf(v.y * sc.y + sh.y, 0.f);
  v.z = fmaxf(v.z * sc.z + sh.z, 0.f);
  v.w = fmaxf(v.w * sc.w + sh.w, 0.f);
  *(float4*)&out[(size_t)g * 4] = v;
}

extern "C" void kernel_launch(void* const* d_in, const int* in_sizes, int n_in,
                              void* d_out, int out_size, void* d_ws, size_t ws_size,
                              hipStream_t stream) {
  const float* x     = (const float*)d_in[0];
  const float* W     = (const float*)d_in[1];
  const float* bias  = (const float*)d_in[2];
  const float* resW  = (const float*)d_in[3];
  const float* gamma = (const float*)d_in[4];
  const float* beta  = (const float*)d_in[5];
  const int*   ei    = (const int*)d_in[6];
  const int* esrc = ei;        // edge_index[0]
  const int* edst = ei + NE;   // edge_index[1]
  float* out = (float*)d_out;

  char* ws = (char*)d_ws;
  size_t off = 0;
  unsigned short* hbf = (unsigned short*)(ws + off); off += (size_t)NN * DD * 2;  // 12.8 MB
  int*   deg  = (int*)(ws + off);   off += (size_t)NN * 4;
  int*   cur  = (int*)(ws + off);   off += (size_t)NN * 4;   // contiguous with deg for one memset
  int*   offs = (int*)(ws + off);   off += (size_t)(NN + 4) * 4;
  float* dinv = (float*)(ws + off); off += (size_t)NN * 4;
  int*   csr  = (int*)(ws + off);   off += (size_t)NE * 4;   // 3.2 MB
  float2* part = (float2*)(ws + off); off += (size_t)512 * 128 * sizeof(float2);
  float* scale = (float*)(ws + off); off += 128 * 4;
  float* shift = (float*)(ws + off); off += 128 * 4;

  hipMemsetAsync(deg, 0, (size_t)NN * 8, stream);  // zero deg + cur

  k_deg    <<<(NE + 255) / 256, 256, 0, stream>>>(edst, deg);
  k_dinv   <<<(NN + 255) / 256, 256, 0, stream>>>(deg, dinv);
  k_scan   <<<1, 1024, 0, stream>>>(deg, offs);
  k_scatter<<<(NE + 255) / 256, 256, 0, stream>>>(esrc, edst, offs, cur, csr);
  k_gemm   <<<(NN / 16 + 3) / 4, 256, 0, stream>>>(x, W, resW, hbf, out);
  k_agg    <<<(NN + 3) / 4, 256, 0, stream>>>(hbf, dinv, offs, csr, bias, out);
  k_stats  <<<512, 256, 0, stream>>>(out, part);
  k_statfin<<<1, 128, 0, stream>>>(part, gamma, beta, scale, shift);
  k_bnrelu <<<(NN * DD / 4) / 256, 256, 0, stream>>>(out, scale, shift);
}

// Round 11
// 285.110 us; speedup vs baseline: 1.2577x; 1.2577x over previous
//
#include <hip/hip_runtime.h>
#include <stdint.h>

#define NN 50000
#define NE 800000
#define DD 128
#define BN_EPS 1e-5f
#define NBLK 196  // ceil(NN/256)

typedef __attribute__((ext_vector_type(8))) short bf16x8;
typedef __attribute__((ext_vector_type(4))) float f32x4;

static __device__ __forceinline__ unsigned short f2bf(float f) {
  unsigned u = __float_as_uint(f);
  u += 0x7fffu + ((u >> 16) & 1u);
  return (unsigned short)(u >> 16);
}
static __device__ __forceinline__ float bf2f(unsigned short s) {
  return __uint_as_float(((unsigned)s) << 16);
}

// ---- phase 1: degree count (in-degree, self-loop added later as +1) ----
__global__ __launch_bounds__(256) void k_deg(const int* __restrict__ dst, int* __restrict__ deg) {
  int e = blockIdx.x * 256 + threadIdx.x;
  if (e < NE) atomicAdd(&deg[dst[e]], 1);
}

// ---- phase 2: hierarchical exclusive scan of degrees -> CSR row offsets ----
// scan1: per-block sums (+ dinv fused, it reads deg anyway)
__global__ __launch_bounds__(256) void k_scan1(const int* __restrict__ deg,
                                               float* __restrict__ dinv,
                                               int* __restrict__ bsum) {
  const int t = threadIdx.x;
  const int i = blockIdx.x * 256 + t;
  const int d = (i < NN) ? deg[i] : 0;
  if (i < NN) dinv[i] = rsqrtf((float)(d + 1));  // +1 self-loop; always >0
  __shared__ int red[256];
  red[t] = d;
  __syncthreads();
  for (int off = 128; off > 0; off >>= 1) {
    if (t < off) red[t] += red[t + off];
    __syncthreads();
  }
  if (t == 0) bsum[blockIdx.x] = red[0];
}

// scan2: single block scans the NBLK block sums -> exclusive prefix (in place)
__global__ __launch_bounds__(256) void k_scan2(int* __restrict__ bsum) {
  const int t = threadIdx.x;
  const int v = (t < NBLK) ? bsum[t] : 0;
  __shared__ int s[256];
  s[t] = v;
  __syncthreads();
  for (int off = 1; off < 256; off <<= 1) {  // Hillis-Steele inclusive
    int u = (t >= off) ? s[t - off] : 0;
    __syncthreads();
    s[t] += u;
    __syncthreads();
  }
  if (t < NBLK) bsum[t] = s[t] - v;  // exclusive = inclusive - self
}

// scan3: local 256-elem scan + block prefix -> offs
__global__ __launch_bounds__(256) void k_scan3(const int* __restrict__ deg,
                                               const int* __restrict__ bpref,
                                               int* __restrict__ offs) {
  const int t = threadIdx.x;
  const int i = blockIdx.x * 256 + t;
  const int d = (i < NN) ? deg[i] : 0;
  __shared__ int s[256];
  s[t] = d;
  __syncthreads();
  for (int off = 1; off < 256; off <<= 1) {
    int u = (t >= off) ? s[t - off] : 0;
    __syncthreads();
    s[t] += u;
    __syncthreads();
  }
  const int incl = s[t];
  if (i < NN) offs[i] = bpref[blockIdx.x] + incl - d;
  if (i == NN - 1) offs[NN] = bpref[blockIdx.x] + incl;  // == NE
}

// ---- phase 3: bucket-scatter edges into CSR by dst ----
__global__ __launch_bounds__(256) void k_scatter(const int* __restrict__ src, const int* __restrict__ dst,
                                                 const int* __restrict__ offs, int* __restrict__ cur,
                                                 int* __restrict__ csr) {
  int e = blockIdx.x * 256 + threadIdx.x;
  if (e < NE) {
    int d = dst[e];
    int slot = atomicAdd(&cur[d], 1);
    csr[offs[d] + slot] = src[e];
  }
}

// ---- phase 4: fused dual GEMM  h = x@W.T (bf16 out, ws)  and  res = x@res_W.T (f32, d_out) ----
// mfma_f32_16x16x32_bf16. A: row=lane&15, k=(lane>>4)*8+i. B: col=lane&15, k=(lane>>4)*8+i.
// C/D: col=lane&15, row=(lane>>4)*4+reg  [measured: learn_hip m89].
__global__ __launch_bounds__(256) void k_gemm(const float* __restrict__ x,
                                              const float* __restrict__ W,
                                              const float* __restrict__ resW,
                                              unsigned short* __restrict__ hbf,
                                              float* __restrict__ resout) {
  __shared__ unsigned short Bl[128][136];  // +8 bf16 pad: row stride 272B = 16B-aligned, ~2-way banks (free)
  const int tid = threadIdx.x;
  const int wave = tid >> 6, lane = tid & 63;
  const int rt = blockIdx.x * 4 + wave;    // 16-row tile per wave
  const int rl = lane & 15, kg = lane >> 4;
  const bool valid = rt < (NN / 16);       // NN divisible by 16
  bf16x8 a[4];
  if (valid) {
    const int grow = rt * 16 + rl;
    for (int ks = 0; ks < 4; ++ks) {
      const float* xp = x + (size_t)grow * DD + ks * 32 + kg * 8;
      float4 v0 = *(const float4*)xp;
      float4 v1 = *(const float4*)(xp + 4);
      bf16x8 af;
      af[0] = (short)f2bf(v0.x); af[1] = (short)f2bf(v0.y);
      af[2] = (short)f2bf(v0.z); af[3] = (short)f2bf(v0.w);
      af[4] = (short)f2bf(v1.x); af[5] = (short)f2bf(v1.y);
      af[6] = (short)f2bf(v1.z); af[7] = (short)f2bf(v1.w);
      a[ks] = af;
    }
  }
  for (int pass = 0; pass < 2; ++pass) {   // pass0: W -> h(bf16); pass1: res_W -> d_out(f32)
    const float* Wp = pass ? resW : W;
    __syncthreads();
    for (int idx = tid; idx < DD * DD; idx += 256) {
      Bl[idx >> 7][idx & 127] = f2bf(Wp[idx]);  // B[k][col] = W[col][k] => rows of W as-is
    }
    __syncthreads();
    if (!valid) continue;
    for (int ct = 0; ct < 8; ++ct) {
      f32x4 acc = {0.f, 0.f, 0.f, 0.f};
      for (int ks = 0; ks < 4; ++ks) {
        bf16x8 b = *(const bf16x8*)&Bl[ct * 16 + rl][ks * 32 + kg * 8];
        acc = __builtin_amdgcn_mfma_f32_16x16x32_bf16(a[ks], b, acc, 0, 0, 0);
      }
      const int col = ct * 16 + rl;
      for (int r = 0; r < 4; ++r) {
        const int row = rt * 16 + kg * 4 + r;
        if (pass == 0) hbf[(size_t)row * DD + col] = f2bf(acc[r]);
        else           resout[(size_t)row * DD + col] = acc[r];
      }
    }
  }
}

// ---- phase 5: per-node aggregation. One wave owns one dst node; lane covers 2 cols. ----
__global__ __launch_bounds__(256) void k_agg(const unsigned short* __restrict__ hbf,
                                             const float* __restrict__ dinv,
                                             const int* __restrict__ offs,
                                             const int* __restrict__ csr,
                                             const float* __restrict__ bias,
                                             float* __restrict__ out) {
  const int wave = threadIdx.x >> 6, lane = threadIdx.x & 63;
  const int i = blockIdx.x * 4 + wave;
  if (i >= NN) return;
  const float di = dinv[i];
  const int c0 = lane * 2;
  const unsigned hv = *(const unsigned*)&hbf[(size_t)i * DD + c0];  // self-loop term
  const float w = di * di;
  float ax = bf2f((unsigned short)(hv & 0xffffu)) * w;
  float ay = bf2f((unsigned short)(hv >> 16)) * w;
  const int beg = offs[i], end = offs[i + 1];
  for (int base = beg; base < end; base += 64) {
    const int e = base + lane;
    int s = 0; float nrm = 0.f;
    if (e < end) { s = csr[e]; nrm = dinv[s] * di; }  // batch 64 edge headers per wave
    const int cnt = min(64, end - base);
    for (int d = 0; d < cnt; ++d) {
      const int ss = __shfl(s, d);
      const float nn = __shfl(nrm, d);
      const unsigned hh = *(const unsigned*)&hbf[(size_t)ss * DD + c0];  // coalesced 256B/row
      ax += bf2f((unsigned short)(hh & 0xffffu)) * nn;
      ay += bf2f((unsigned short)(hh >> 16)) * nn;
    }
  }
  float2 r = *(const float2*)&out[(size_t)i * DD + c0];  // res projection from GEMM pass1
  r.x += ax + bias[c0];
  r.y += ay + bias[c0 + 1];
  *(float2*)&out[(size_t)i * DD + c0] = r;
}

// ---- phase 6: BN column stats, two-stage (block partials -> tiny reduce) ----
__global__ __launch_bounds__(256) void k_stats(const float* __restrict__ out, float2* __restrict__ part) {
  const int t = threadIdx.x;
  const int g = blockIdx.x * 256 + t;  // 512 blocks => 1024 threads per column
  const int c = g & 127;
  float s = 0.f, q = 0.f;
  for (int r = g >> 7; r < NN; r += 1024) {
    const float v = out[(size_t)r * DD + c];
    s += v; q += v * v;
  }
  __shared__ float2 red[256];
  red[t] = make_float2(s, q);
  __syncthreads();
  if (t < 128) {
    float2 a = red[t], b = red[t + 128];
    part[blockIdx.x * 128 + t] = make_float2(a.x + b.x, a.y + b.y);
  }
}

__global__ __launch_bounds__(128) void k_statfin(const float2* __restrict__ part,
                                                 const float* __restrict__ gamma,
                                                 const float* __restrict__ beta,
                                                 float* __restrict__ scale,
                                                 float* __restrict__ shift) {
  const int c = threadIdx.x;
  float s = 0.f, q = 0.f;
  for (int b = 0; b < 512; ++b) { float2 p = part[b * 128 + c]; s += p.x; q += p.y; }
  const float mean = s * (1.0f / NN);
  const float var = q * (1.0f / NN) - mean * mean;  // jnp.var is biased (divide by N)
  const float inv = rsqrtf(var + BN_EPS);
  const float sc = gamma[c] * inv;
  scale[c] = sc;
  shift[c] = beta[c] - mean * sc;
}

// ---- phase 7: BN apply + ReLU, in place on d_out ----
__global__ __launch_bounds__(256) void k_bnrelu(float* __restrict__ out,
                                                const float* __restrict__ scale,
                                                const float* __restrict__ shift) {
  const int g = blockIdx.x * 256 + threadIdx.x;  // exactly NN*DD/4 threads
  const int c0 = (g & 31) * 4;
  float4 v = *(float4*)&out[(size_t)g * 4];
  const float4 sc = *(const float4*)&scale[c0];
  const float4 sh = *(const float4*)&shift[c0];
  v.x = fmaxf(v.x * sc.x + sh.x, 0.f);
  v.y = fmaxf(v.y * sc.y + sh.y, 0.f);
  v.z = fmaxf(v.z * sc.z + sh.z, 0.f);
  v.w = fmaxf(v.w * sc.w + sh.w, 0.f);
  *(float4*)&out[(size_t)g * 4] = v;
}

extern "C" void kernel_launch(void* const* d_in, const int* in_sizes, int n_in,
                              void* d_out, int out_size, void* d_ws, size_t ws_size,
                              hipStream_t stream) {
  const float* x     = (const float*)d_in[0];
  const float* W     = (const float*)d_in[1];
  const float* bias  = (const float*)d_in[2];
  const float* resW  = (const float*)d_in[3];
  const float* gamma = (const float*)d_in[4];
  const float* beta  = (const float*)d_in[5];
  const int*   ei    = (const int*)d_in[6];
  const int* esrc = ei;        // edge_index[0]
  const int* edst = ei + NE;   // edge_index[1]
  float* out = (float*)d_out;

  char* ws = (char*)d_ws;
  size_t off = 0;
  unsigned short* hbf = (unsigned short*)(ws + off); off += (size_t)NN * DD * 2;  // 12.8 MB
  int*   deg  = (int*)(ws + off);   off += (size_t)NN * 4;
  int*   cur  = (int*)(ws + off);   off += (size_t)NN * 4;   // contiguous with deg for one memset
  int*   offs = (int*)(ws + off);   off += (size_t)(NN + 4) * 4;
  float* dinv = (float*)(ws + off); off += (size_t)NN * 4;
  int*   csr  = (int*)(ws + off);   off += (size_t)NE * 4;   // 3.2 MB
  int*   bsum = (int*)(ws + off);   off += 256 * 4;          // block sums for hierarchical scan
  float2* part = (float2*)(ws + off); off += (size_t)512 * 128 * sizeof(float2);
  float* scale = (float*)(ws + off); off += 128 * 4;
  float* shift = (float*)(ws + off); off += 128 * 4;

  hipMemsetAsync(deg, 0, (size_t)NN * 8, stream);  // zero deg + cur

  k_deg    <<<(NE + 255) / 256, 256, 0, stream>>>(edst, deg);
  k_scan1  <<<NBLK, 256, 0, stream>>>(deg, dinv, bsum);
  k_scan2  <<<1, 256, 0, stream>>>(bsum);
  k_scan3  <<<NBLK, 256, 0, stream>>>(deg, bsum, offs);
  k_scatter<<<(NE + 255) / 256, 256, 0, stream>>>(esrc, edst, offs, cur, csr);
  k_gemm   <<<(NN / 16 + 3) / 4, 256, 0, stream>>>(x, W, resW, hbf, out);
  k_agg    <<<(NN + 3) / 4, 256, 0, stream>>>(hbf, dinv, offs, csr, bias, out);
  k_stats  <<<512, 256, 0, stream>>>(out, part);
  k_statfin<<<1, 128, 0, stream>>>(part, gamma, beta, scale, shift);
  k_bnrelu <<<(NN * DD / 4) / 256, 256, 0, stream>>>(out, scale, shift);
}

// Round 12
// 262.465 us; speedup vs baseline: 1.3662x; 1.0863x over previous
//
#include <hip/hip_runtime.h>
#include <stdint.h>

#define NN 50000
#define NE 800000
#define DD 128
#define BN_EPS 1e-5f
#define NBLK 196  // ceil(NN/256)

typedef __attribute__((ext_vector_type(8))) short bf16x8;
typedef __attribute__((ext_vector_type(4))) float f32x4;

static __device__ __forceinline__ unsigned short f2bf(float f) {
  unsigned u = __float_as_uint(f);
  u += 0x7fffu + ((u >> 16) & 1u);
  return (unsigned short)(u >> 16);
}
static __device__ __forceinline__ float bf2f(unsigned short s) {
  return __uint_as_float(((unsigned)s) << 16);
}

// ---- phase 1: degree count (in-degree, self-loop added later as +1) ----
__global__ __launch_bounds__(256) void k_deg(const int* __restrict__ dst, int* __restrict__ deg) {
  int e = blockIdx.x * 256 + threadIdx.x;
  if (e < NE) atomicAdd(&deg[dst[e]], 1);
}

// ---- phase 2: hierarchical exclusive scan of degrees -> CSR row offsets ----
__global__ __launch_bounds__(256) void k_scan1(const int* __restrict__ deg,
                                               float* __restrict__ dinv,
                                               int* __restrict__ bsum) {
  const int t = threadIdx.x;
  const int i = blockIdx.x * 256 + t;
  const int d = (i < NN) ? deg[i] : 0;
  if (i < NN) dinv[i] = rsqrtf((float)(d + 1));  // +1 self-loop; always >0
  __shared__ int red[256];
  red[t] = d;
  __syncthreads();
  for (int off = 128; off > 0; off >>= 1) {
    if (t < off) red[t] += red[t + off];
    __syncthreads();
  }
  if (t == 0) bsum[blockIdx.x] = red[0];
}

__global__ __launch_bounds__(256) void k_scan2(int* __restrict__ bsum) {
  const int t = threadIdx.x;
  const int v = (t < NBLK) ? bsum[t] : 0;
  __shared__ int s[256];
  s[t] = v;
  __syncthreads();
  for (int off = 1; off < 256; off <<= 1) {  // Hillis-Steele inclusive
    int u = (t >= off) ? s[t - off] : 0;
    __syncthreads();
    s[t] += u;
    __syncthreads();
  }
  if (t < NBLK) bsum[t] = s[t] - v;  // exclusive = inclusive - self
}

__global__ __launch_bounds__(256) void k_scan3(const int* __restrict__ deg,
                                               const int* __restrict__ bpref,
                                               int* __restrict__ offs) {
  const int t = threadIdx.x;
  const int i = blockIdx.x * 256 + t;
  const int d = (i < NN) ? deg[i] : 0;
  __shared__ int s[256];
  s[t] = d;
  __syncthreads();
  for (int off = 1; off < 256; off <<= 1) {
    int u = (t >= off) ? s[t - off] : 0;
    __syncthreads();
    s[t] += u;
    __syncthreads();
  }
  const int incl = s[t];
  if (i < NN) offs[i] = bpref[blockIdx.x] + incl - d;
  if (i == NN - 1) offs[NN] = bpref[blockIdx.x] + incl;  // == NE
}

// ---- phase 3: bucket-scatter edges into CSR by dst ----
__global__ __launch_bounds__(256) void k_scatter(const int* __restrict__ src, const int* __restrict__ dst,
                                                 const int* __restrict__ offs, int* __restrict__ cur,
                                                 int* __restrict__ csr) {
  int e = blockIdx.x * 256 + threadIdx.x;
  if (e < NE) {
    int d = dst[e];
    int slot = atomicAdd(&cur[d], 1);
    csr[offs[d] + slot] = src[e];
  }
}

// ---- phase 4: fused dual GEMM  h = x@W.T (bf16 out, ws)  and  res = x@res_W.T (f32, d_out) ----
__global__ __launch_bounds__(256) void k_gemm(const float* __restrict__ x,
                                              const float* __restrict__ W,
                                              const float* __restrict__ resW,
                                              unsigned short* __restrict__ hbf,
                                              float* __restrict__ resout) {
  __shared__ unsigned short Bl[128][136];
  const int tid = threadIdx.x;
  const int wave = tid >> 6, lane = tid & 63;
  const int rt = blockIdx.x * 4 + wave;    // 16-row tile per wave
  const int rl = lane & 15, kg = lane >> 4;
  const bool valid = rt < (NN / 16);
  bf16x8 a[4];
  if (valid) {
    const int grow = rt * 16 + rl;
    for (int ks = 0; ks < 4; ++ks) {
      const float* xp = x + (size_t)grow * DD + ks * 32 + kg * 8;
      float4 v0 = *(const float4*)xp;
      float4 v1 = *(const float4*)(xp + 4);
      bf16x8 af;
      af[0] = (short)f2bf(v0.x); af[1] = (short)f2bf(v0.y);
      af[2] = (short)f2bf(v0.z); af[3] = (short)f2bf(v0.w);
      af[4] = (short)f2bf(v1.x); af[5] = (short)f2bf(v1.y);
      af[6] = (short)f2bf(v1.z); af[7] = (short)f2bf(v1.w);
      a[ks] = af;
    }
  }
  for (int pass = 0; pass < 2; ++pass) {
    const float* Wp = pass ? resW : W;
    __syncthreads();
    for (int idx = tid; idx < DD * DD; idx += 256) {
      Bl[idx >> 7][idx & 127] = f2bf(Wp[idx]);
    }
    __syncthreads();
    if (!valid) continue;
    for (int ct = 0; ct < 8; ++ct) {
      f32x4 acc = {0.f, 0.f, 0.f, 0.f};
      for (int ks = 0; ks < 4; ++ks) {
        bf16x8 b = *(const bf16x8*)&Bl[ct * 16 + rl][ks * 32 + kg * 8];
        acc = __builtin_amdgcn_mfma_f32_16x16x32_bf16(a[ks], b, acc, 0, 0, 0);
      }
      const int col = ct * 16 + rl;
      for (int r = 0; r < 4; ++r) {
        const int row = rt * 16 + kg * 4 + r;
        if (pass == 0) hbf[(size_t)row * DD + col] = f2bf(acc[r]);
        else           resout[(size_t)row * DD + col] = acc[r];
      }
    }
  }
}

// ---- phase 5: per-node aggregation, v2: 16B gathers, 4 edges in flight per wave-load ----
// quarter q = lane>>4 owns edge (d+q); li = lane&15 owns cols li*8..li*8+7 (16B of bf16 row).
// After the loop, cross-quarter butterfly (xor 16, 32) reduces 4 partials; q==0 writes.
__global__ __launch_bounds__(256) void k_agg(const unsigned short* __restrict__ hbf,
                                             const float* __restrict__ dinv,
                                             const int* __restrict__ offs,
                                             const int* __restrict__ csr,
                                             const float* __restrict__ bias,
                                             float* __restrict__ out) {
  const int wave = threadIdx.x >> 6, lane = threadIdx.x & 63;
  const int i = blockIdx.x * 4 + wave;
  if (i >= NN) return;
  const float di = dinv[i];
  const int q = lane >> 4;
  const int li = lane & 15;
  const int c0 = li * 8;
  float ax[8];
  #pragma unroll
  for (int j = 0; j < 8; ++j) ax[j] = 0.f;

  const int beg = offs[i], end = offs[i + 1];
  for (int base = beg; base < end; base += 64) {
    int s = 0; float nrm = 0.f;
    const int e = base + lane;
    if (e < end) { s = csr[e]; nrm = dinv[s] * di; }  // invalid lanes: s=0, nrm=0 (branch-free)
    const int cnt = min(64, end - base);
    #pragma unroll 2
    for (int d = 0; d < cnt; d += 4) {
      const int ss = __shfl(s, d + q);       // d+q <= 63 always
      const float nn = __shfl(nrm, d + q);
      const uint4 hv = *(const uint4*)&hbf[(size_t)ss * DD + c0];  // 4x256B segments per wave-load
      ax[0] += bf2f((unsigned short)(hv.x & 0xffffu)) * nn;
      ax[1] += bf2f((unsigned short)(hv.x >> 16)) * nn;
      ax[2] += bf2f((unsigned short)(hv.y & 0xffffu)) * nn;
      ax[3] += bf2f((unsigned short)(hv.y >> 16)) * nn;
      ax[4] += bf2f((unsigned short)(hv.z & 0xffffu)) * nn;
      ax[5] += bf2f((unsigned short)(hv.z >> 16)) * nn;
      ax[6] += bf2f((unsigned short)(hv.w & 0xffffu)) * nn;
      ax[7] += bf2f((unsigned short)(hv.w >> 16)) * nn;
    }
  }
  // cross-quarter reduction: lanes {li, li+16, li+32, li+48} hold partials of cols li*8..+7
  #pragma unroll
  for (int j = 0; j < 8; ++j) {
    ax[j] += __shfl_xor(ax[j], 16);
    ax[j] += __shfl_xor(ax[j], 32);
  }
  if (q == 0) {
    // self-loop term
    const float w = di * di;
    const uint4 hv = *(const uint4*)&hbf[(size_t)i * DD + c0];
    ax[0] += bf2f((unsigned short)(hv.x & 0xffffu)) * w;
    ax[1] += bf2f((unsigned short)(hv.x >> 16)) * w;
    ax[2] += bf2f((unsigned short)(hv.y & 0xffffu)) * w;
    ax[3] += bf2f((unsigned short)(hv.y >> 16)) * w;
    ax[4] += bf2f((unsigned short)(hv.z & 0xffffu)) * w;
    ax[5] += bf2f((unsigned short)(hv.z >> 16)) * w;
    ax[6] += bf2f((unsigned short)(hv.w & 0xffffu)) * w;
    ax[7] += bf2f((unsigned short)(hv.w >> 16)) * w;
    // out = agg + bias + res (res already in out from GEMM pass1)
    float4 r0 = *(const float4*)&out[(size_t)i * DD + c0];
    float4 r1 = *(const float4*)&out[(size_t)i * DD + c0 + 4];
    const float4 b0 = *(const float4*)&bias[c0];
    const float4 b1 = *(const float4*)&bias[c0 + 4];
    r0.x += ax[0] + b0.x; r0.y += ax[1] + b0.y;
    r0.z += ax[2] + b0.z; r0.w += ax[3] + b0.w;
    r1.x += ax[4] + b1.x; r1.y += ax[5] + b1.y;
    r1.z += ax[6] + b1.z; r1.w += ax[7] + b1.w;
    *(float4*)&out[(size_t)i * DD + c0] = r0;
    *(float4*)&out[(size_t)i * DD + c0 + 4] = r1;
  }
}

// ---- phase 6: BN column stats, two-stage (block partials -> tiny reduce) ----
__global__ __launch_bounds__(256) void k_stats(const float* __restrict__ out, float2* __restrict__ part) {
  const int t = threadIdx.x;
  const int g = blockIdx.x * 256 + t;  // 512 blocks => 1024 threads per column
  const int c = g & 127;
  float s = 0.f, q = 0.f;
  for (int r = g >> 7; r < NN; r += 1024) {
    const float v = out[(size_t)r * DD + c];
    s += v; q += v * v;
  }
  __shared__ float2 red[256];
  red[t] = make_float2(s, q);
  __syncthreads();
  if (t < 128) {
    float2 a = red[t], b = red[t + 128];
    part[blockIdx.x * 128 + t] = make_float2(a.x + b.x, a.y + b.y);
  }
}

__global__ __launch_bounds__(128) void k_statfin(const float2* __restrict__ part,
                                                 const float* __restrict__ gamma,
                                                 const float* __restrict__ beta,
                                                 float* __restrict__ scale,
                                                 float* __restrict__ shift) {
  const int c = threadIdx.x;
  float s = 0.f, q = 0.f;
  for (int b = 0; b < 512; ++b) { float2 p = part[b * 128 + c]; s += p.x; q += p.y; }
  const float mean = s * (1.0f / NN);
  const float var = q * (1.0f / NN) - mean * mean;  // jnp.var is biased (divide by N)
  const float inv = rsqrtf(var + BN_EPS);
  const float sc = gamma[c] * inv;
  scale[c] = sc;
  shift[c] = beta[c] - mean * sc;
}

// ---- phase 7: BN apply + ReLU, in place on d_out ----
__global__ __launch_bounds__(256) void k_bnrelu(float* __restrict__ out,
                                                const float* __restrict__ scale,
                                                const float* __restrict__ shift) {
  const int g = blockIdx.x * 256 + threadIdx.x;  // exactly NN*DD/4 threads
  const int c0 = (g & 31) * 4;
  float4 v = *(float4*)&out[(size_t)g * 4];
  const float4 sc = *(const float4*)&scale[c0];
  const float4 sh = *(const float4*)&shift[c0];
  v.x = fmaxf(v.x * sc.x + sh.x, 0.f);
  v.y = fmaxf(v.y * sc.y + sh.y, 0.f);
  v.z = fmaxf(v.z * sc.z + sh.z, 0.f);
  v.w = fmaxf(v.w * sc.w + sh.w, 0.f);
  *(float4*)&out[(size_t)g * 4] = v;
}

extern "C" void kernel_launch(void* const* d_in, const int* in_sizes, int n_in,
                              void* d_out, int out_size, void* d_ws, size_t ws_size,
                              hipStream_t stream) {
  const float* x     = (const float*)d_in[0];
  const float* W     = (const float*)d_in[1];
  const float* bias  = (const float*)d_in[2];
  const float* resW  = (const float*)d_in[3];
  const float* gamma = (const float*)d_in[4];
  const float* beta  = (const float*)d_in[5];
  const int*   ei    = (const int*)d_in[6];
  const int* esrc = ei;        // edge_index[0]
  const int* edst = ei + NE;   // edge_index[1]
  float* out = (float*)d_out;

  char* ws = (char*)d_ws;
  size_t off = 0;
  unsigned short* hbf = (unsigned short*)(ws + off); off += (size_t)NN * DD * 2;  // 12.8 MB
  int*   deg  = (int*)(ws + off);   off += (size_t)NN * 4;
  int*   cur  = (int*)(ws + off);   off += (size_t)NN * 4;   // contiguous with deg for one memset
  int*   offs = (int*)(ws + off);   off += (size_t)(NN + 4) * 4;
  float* dinv = (float*)(ws + off); off += (size_t)NN * 4;
  int*   csr  = (int*)(ws + off);   off += (size_t)NE * 4;   // 3.2 MB
  int*   bsum = (int*)(ws + off);   off += 256 * 4;          // block sums for hierarchical scan
  float2* part = (float2*)(ws + off); off += (size_t)512 * 128 * sizeof(float2);
  float* scale = (float*)(ws + off); off += 128 * 4;
  float* shift = (float*)(ws + off); off += 128 * 4;

  hipMemsetAsync(deg, 0, (size_t)NN * 8, stream);  // zero deg + cur

  k_deg    <<<(NE + 255) / 256, 256, 0, stream>>>(edst, deg);
  k_scan1  <<<NBLK, 256, 0, stream>>>(deg, dinv, bsum);
  k_scan2  <<<1, 256, 0, stream>>>(bsum);
  k_scan3  <<<NBLK, 256, 0, stream>>>(deg, bsum, offs);
  k_scatter<<<(NE + 255) / 256, 256, 0, stream>>>(esrc, edst, offs, cur, csr);
  k_gemm   <<<(NN / 16 + 3) / 4, 256, 0, stream>>>(x, W, resW, hbf, out);
  k_agg    <<<(NN + 3) / 4, 256, 0, stream>>>(hbf, dinv, offs, csr, bias, out);
  k_stats  <<<512, 256, 0, stream>>>(out, part);
  k_statfin<<<1, 128, 0, stream>>>(part, gamma, beta, scale, shift);
  k_bnrelu <<<(NN * DD / 4) / 256, 256, 0, stream>>>(out, scale, shift);
}

// Round 16
// 233.191 us; speedup vs baseline: 1.5378x; 1.1255x over previous
//
#include <hip/hip_runtime.h>
#include <stdint.h>

#define NN 50000
#define NE 800000
#define DD 128
#define BN_EPS 1e-5f
#define NBLK 196  // ceil(NN/256)

typedef __attribute__((ext_vector_type(8))) short bf16x8;
typedef __attribute__((ext_vector_type(4))) float f32x4;

static __device__ __forceinline__ unsigned short f2bf(float f) {
  unsigned u = __float_as_uint(f);
  u += 0x7fffu + ((u >> 16) & 1u);
  return (unsigned short)(u >> 16);
}
static __device__ __forceinline__ float bf2f(unsigned short s) {
  return __uint_as_float(((unsigned)s) << 16);
}

// ---- phase 1: degree count + slot assignment (atomicAdd return = unique slot per edge) ----
__global__ __launch_bounds__(256) void k_deg(const int* __restrict__ dst, int* __restrict__ deg,
                                             int* __restrict__ slotbuf) {
  int e = blockIdx.x * 256 + threadIdx.x;
  if (e < NE) slotbuf[e] = atomicAdd(&deg[dst[e]], 1);
}

// ---- phase 2: hierarchical exclusive scan of degrees -> CSR row offsets ----
__global__ __launch_bounds__(256) void k_scan1(const int* __restrict__ deg,
                                               float* __restrict__ dinv,
                                               int* __restrict__ bsum) {
  const int t = threadIdx.x;
  const int i = blockIdx.x * 256 + t;
  const int d = (i < NN) ? deg[i] : 0;
  if (i < NN) dinv[i] = rsqrtf((float)(d + 1));  // +1 self-loop; always >0
  __shared__ int red[256];
  red[t] = d;
  __syncthreads();
  for (int off = 128; off > 0; off >>= 1) {
    if (t < off) red[t] += red[t + off];
    __syncthreads();
  }
  if (t == 0) bsum[blockIdx.x] = red[0];
}

__global__ __launch_bounds__(256) void k_scan2(int* __restrict__ bsum) {
  const int t = threadIdx.x;
  const int v = (t < NBLK) ? bsum[t] : 0;
  __shared__ int s[256];
  s[t] = v;
  __syncthreads();
  for (int off = 1; off < 256; off <<= 1) {  // Hillis-Steele inclusive
    int u = (t >= off) ? s[t - off] : 0;
    __syncthreads();
    s[t] += u;
    __syncthreads();
  }
  if (t < NBLK) bsum[t] = s[t] - v;  // exclusive = inclusive - self
}

__global__ __launch_bounds__(256) void k_scan3(const int* __restrict__ deg,
                                               const int* __restrict__ bpref,
                                               int* __restrict__ offs) {
  const int t = threadIdx.x;
  const int i = blockIdx.x * 256 + t;
  const int d = (i < NN) ? deg[i] : 0;
  __shared__ int s[256];
  s[t] = d;
  __syncthreads();
  for (int off = 1; off < 256; off <<= 1) {
    int u = (t >= off) ? s[t - off] : 0;
    __syncthreads();
    s[t] += u;
    __syncthreads();
  }
  const int incl = s[t];
  if (i < NN) offs[i] = bpref[blockIdx.x] + incl - d;
  if (i == NN - 1) offs[NN] = bpref[blockIdx.x] + incl;  // == NE
}

// ---- phase 3: scatter edges into CSR (no atomics; slot precomputed in k_deg) ----
__global__ __launch_bounds__(256) void k_scatter(const int* __restrict__ src, const int* __restrict__ dst,
                                                 const int* __restrict__ offs,
                                                 const int* __restrict__ slotbuf,
                                                 int* __restrict__ csr) {
  int e = blockIdx.x * 256 + threadIdx.x;
  if (e < NE) {
    csr[offs[dst[e]] + slotbuf[e]] = src[e];
  }
}

// ---- phase 4: fused dual GEMM  h = x@W.T (bf16 out, ws)  and  res = x@res_W.T (f32, d_out) ----
__global__ __launch_bounds__(256) void k_gemm(const float* __restrict__ x,
                                              const float* __restrict__ W,
                                              const float* __restrict__ resW,
                                              unsigned short* __restrict__ hbf,
                                              float* __restrict__ resout) {
  __shared__ unsigned short Bl[128][136];
  const int tid = threadIdx.x;
  const int wave = tid >> 6, lane = tid & 63;
  const int rt = blockIdx.x * 4 + wave;    // 16-row tile per wave
  const int rl = lane & 15, kg = lane >> 4;
  const bool valid = rt < (NN / 16);
  bf16x8 a[4];
  if (valid) {
    const int grow = rt * 16 + rl;
    for (int ks = 0; ks < 4; ++ks) {
      const float* xp = x + (size_t)grow * DD + ks * 32 + kg * 8;
      float4 v0 = *(const float4*)xp;
      float4 v1 = *(const float4*)(xp + 4);
      bf16x8 af;
      af[0] = (short)f2bf(v0.x); af[1] = (short)f2bf(v0.y);
      af[2] = (short)f2bf(v0.z); af[3] = (short)f2bf(v0.w);
      af[4] = (short)f2bf(v1.x); af[5] = (short)f2bf(v1.y);
      af[6] = (short)f2bf(v1.z); af[7] = (short)f2bf(v1.w);
      a[ks] = af;
    }
  }
  for (int pass = 0; pass < 2; ++pass) {
    const float* Wp = pass ? resW : W;
    __syncthreads();
    for (int idx = tid; idx < DD * DD; idx += 256) {
      Bl[idx >> 7][idx & 127] = f2bf(Wp[idx]);
    }
    __syncthreads();
    if (!valid) continue;
    for (int ct = 0; ct < 8; ++ct) {
      f32x4 acc = {0.f, 0.f, 0.f, 0.f};
      for (int ks = 0; ks < 4; ++ks) {
        bf16x8 b = *(const bf16x8*)&Bl[ct * 16 + rl][ks * 32 + kg * 8];
        acc = __builtin_amdgcn_mfma_f32_16x16x32_bf16(a[ks], b, acc, 0, 0, 0);
      }
      const int col = ct * 16 + rl;
      for (int r = 0; r < 4; ++r) {
        const int row = rt * 16 + kg * 4 + r;
        if (pass == 0) hbf[(size_t)row * DD + col] = f2bf(acc[r]);
        else           resout[(size_t)row * DD + col] = acc[r];
      }
    }
  }
}

// ---- phase 5: per-node aggregation: 16B gathers, 4 edges in flight per wave-load ----
__global__ __launch_bounds__(256) void k_agg(const unsigned short* __restrict__ hbf,
                                             const float* __restrict__ dinv,
                                             const int* __restrict__ offs,
                                             const int* __restrict__ csr,
                                             const float* __restrict__ bias,
                                             float* __restrict__ out) {
  const int wave = threadIdx.x >> 6, lane = threadIdx.x & 63;
  const int i = blockIdx.x * 4 + wave;
  if (i >= NN) return;
  const float di = dinv[i];
  const int q = lane >> 4;
  const int li = lane & 15;
  const int c0 = li * 8;
  float ax[8];
  #pragma unroll
  for (int j = 0; j < 8; ++j) ax[j] = 0.f;

  const int beg = offs[i], end = offs[i + 1];
  for (int base = beg; base < end; base += 64) {
    int s = 0; float nrm = 0.f;
    const int e = base + lane;
    if (e < end) { s = csr[e]; nrm = dinv[s] * di; }  // invalid lanes: s=0, nrm=0 (branch-free)
    const int cnt = min(64, end - base);
    #pragma unroll 2
    for (int d = 0; d < cnt; d += 4) {
      const int ss = __shfl(s, d + q);       // d+q <= 63 always
      const float nn = __shfl(nrm, d + q);
      const uint4 hv = *(const uint4*)&hbf[(size_t)ss * DD + c0];  // 4x256B segments per wave-load
      ax[0] += bf2f((unsigned short)(hv.x & 0xffffu)) * nn;
      ax[1] += bf2f((unsigned short)(hv.x >> 16)) * nn;
      ax[2] += bf2f((unsigned short)(hv.y & 0xffffu)) * nn;
      ax[3] += bf2f((unsigned short)(hv.y >> 16)) * nn;
      ax[4] += bf2f((unsigned short)(hv.z & 0xffffu)) * nn;
      ax[5] += bf2f((unsigned short)(hv.z >> 16)) * nn;
      ax[6] += bf2f((unsigned short)(hv.w & 0xffffu)) * nn;
      ax[7] += bf2f((unsigned short)(hv.w >> 16)) * nn;
    }
  }
  // cross-quarter reduction: lanes {li, li+16, li+32, li+48} hold partials of cols li*8..+7
  #pragma unroll
  for (int j = 0; j < 8; ++j) {
    ax[j] += __shfl_xor(ax[j], 16);
    ax[j] += __shfl_xor(ax[j], 32);
  }
  if (q == 0) {
    // self-loop term
    const float w = di * di;
    const uint4 hv = *(const uint4*)&hbf[(size_t)i * DD + c0];
    ax[0] += bf2f((unsigned short)(hv.x & 0xffffu)) * w;
    ax[1] += bf2f((unsigned short)(hv.x >> 16)) * w;
    ax[2] += bf2f((unsigned short)(hv.y & 0xffffu)) * w;
    ax[3] += bf2f((unsigned short)(hv.y >> 16)) * w;
    ax[4] += bf2f((unsigned short)(hv.z & 0xffffu)) * w;
    ax[5] += bf2f((unsigned short)(hv.z >> 16)) * w;
    ax[6] += bf2f((unsigned short)(hv.w & 0xffffu)) * w;
    ax[7] += bf2f((unsigned short)(hv.w >> 16)) * w;
    // out = agg + bias + res (res already in out from GEMM pass1)
    float4 r0 = *(const float4*)&out[(size_t)i * DD + c0];
    float4 r1 = *(const float4*)&out[(size_t)i * DD + c0 + 4];
    const float4 b0 = *(const float4*)&bias[c0];
    const float4 b1 = *(const float4*)&bias[c0 + 4];
    r0.x += ax[0] + b0.x; r0.y += ax[1] + b0.y;
    r0.z += ax[2] + b0.z; r0.w += ax[3] + b0.w;
    r1.x += ax[4] + b1.x; r1.y += ax[5] + b1.y;
    r1.z += ax[6] + b1.z; r1.w += ax[7] + b1.w;
    *(float4*)&out[(size_t)i * DD + c0] = r0;
    *(float4*)&out[(size_t)i * DD + c0 + 4] = r1;
  }
}

// ---- phase 6: BN column stats, two-stage (block partials -> tiny reduce) ----
__global__ __launch_bounds__(256) void k_stats(const float* __restrict__ out, float2* __restrict__ part) {
  const int t = threadIdx.x;
  const int g = blockIdx.x * 256 + t;  // 512 blocks => 1024 threads per column
  const int c = g & 127;
  float s = 0.f, q = 0.f;
  for (int r = g >> 7; r < NN; r += 1024) {
    const float v = out[(size_t)r * DD + c];
    s += v; q += v * v;
  }
  __shared__ float2 red[256];
  red[t] = make_float2(s, q);
  __syncthreads();
  if (t < 128) {
    float2 a = red[t], b = red[t + 128];
    part[blockIdx.x * 128 + t] = make_float2(a.x + b.x, a.y + b.y);
  }
}

__global__ __launch_bounds__(128) void k_statfin(const float2* __restrict__ part,
                                                 const float* __restrict__ gamma,
                                                 const float* __restrict__ beta,
                                                 float* __restrict__ scale,
                                                 float* __restrict__ shift) {
  const int c = threadIdx.x;
  float s = 0.f, q = 0.f;
  for (int b = 0; b < 512; ++b) { float2 p = part[b * 128 + c]; s += p.x; q += p.y; }
  const float mean = s * (1.0f / NN);
  const float var = q * (1.0f / NN) - mean * mean;  // jnp.var is biased (divide by N)
  const float inv = rsqrtf(var + BN_EPS);
  const float sc = gamma[c] * inv;
  scale[c] = sc;
  shift[c] = beta[c] - mean * sc;
}

// ---- phase 7: BN apply + ReLU, in place on d_out ----
__global__ __launch_bounds__(256) void k_bnrelu(float* __restrict__ out,
                                                const float* __restrict__ scale,
                                                const float* __restrict__ shift) {
  const int g = blockIdx.x * 256 + threadIdx.x;  // exactly NN*DD/4 threads
  const int c0 = (g & 31) * 4;
  float4 v = *(float4*)&out[(size_t)g * 4];
  const float4 sc = *(const float4*)&scale[c0];
  const float4 sh = *(const float4*)&shift[c0];
  v.x = fmaxf(v.x * sc.x + sh.x, 0.f);
  v.y = fmaxf(v.y * sc.y + sh.y, 0.f);
  v.z = fmaxf(v.z * sc.z + sh.z, 0.f);
  v.w = fmaxf(v.w * sc.w + sh.w, 0.f);
  *(float4*)&out[(size_t)g * 4] = v;
}

extern "C" void kernel_launch(void* const* d_in, const int* in_sizes, int n_in,
                              void* d_out, int out_size, void* d_ws, size_t ws_size,
                              hipStream_t stream) {
  const float* x     = (const float*)d_in[0];
  const float* W     = (const float*)d_in[1];
  const float* bias  = (const float*)d_in[2];
  const float* resW  = (const float*)d_in[3];
  const float* gamma = (const float*)d_in[4];
  const float* beta  = (const float*)d_in[5];
  const int*   ei    = (const int*)d_in[6];
  const int* esrc = ei;        // edge_index[0]
  const int* edst = ei + NE;   // edge_index[1]
  float* out = (float*)d_out;

  char* ws = (char*)d_ws;
  size_t off = 0;
  unsigned short* hbf = (unsigned short*)(ws + off); off += (size_t)NN * DD * 2;  // 12.8 MB
  int*   deg  = (int*)(ws + off);   off += (size_t)NN * 4;
  int*   offs = (int*)(ws + off);   off += (size_t)(NN + 4) * 4;
  float* dinv = (float*)(ws + off); off += (size_t)NN * 4;
  int*   csr  = (int*)(ws + off);   off += (size_t)NE * 4;   // 3.2 MB
  int*   slotbuf = (int*)(ws + off); off += (size_t)NE * 4;  // 3.2 MB (per-edge slot from k_deg)
  int*   bsum = (int*)(ws + off);   off += 256 * 4;          // block sums for hierarchical scan
  float2* part = (float2*)(ws + off); off += (size_t)512 * 128 * sizeof(float2);
  float* scale = (float*)(ws + off); off += 128 * 4;
  float* shift = (float*)(ws + off); off += 128 * 4;

  hipMemsetAsync(deg, 0, (size_t)NN * 4, stream);  // zero deg (cur no longer exists)

  k_deg    <<<(NE + 255) / 256, 256, 0, stream>>>(edst, deg, slotbuf);
  k_scan1  <<<NBLK, 256, 0, stream>>>(deg, dinv, bsum);
  k_scan2  <<<1, 256, 0, stream>>>(bsum);
  k_scan3  <<<NBLK, 256, 0, stream>>>(deg, bsum, offs);
  k_scatter<<<(NE + 255) / 256, 256, 0, stream>>>(esrc, edst, offs, slotbuf, csr);
  k_gemm   <<<(NN / 16 + 3) / 4, 256, 0, stream>>>(x, W, resW, hbf, out);
  k_agg    <<<(NN + 3) / 4, 256, 0, stream>>>(hbf, dinv, offs, csr, bias, out);
  k_stats  <<<512, 256, 0, stream>>>(out, part);
  k_statfin<<<1, 128, 0, stream>>>(part, gamma, beta, scale, shift);
  k_bnrelu <<<(NN * DD / 4) / 256, 256, 0, stream>>>(out, scale, shift);
}